// Round 6
// baseline (72.270 us; speedup 1.0000x reference)
//
#include <hip/hip_runtime.h>

// LiftSplatShoot: out(B,N,3+C,H,W,D) = concat(world, feats_broadcast)
// B=4 N=6 C=80 H=16 W=44 D=59 -> 82,739,712 fp32 (~331 MB). Write-bound.
// Round 6: coordinated phase sweep. 498 blocks x 4 phases; at phase p the
// whole machine writes slabs [498p, 498(p+1)) = one contiguous 83MB window
// (fits L3, DRAM-row friendly), mimicking the fill kernel's linear sweep
// that sustains ~7 TB/s. Block body identical to round 5.

#define BB 4
#define NN 6
#define CC 80
#define HH 16
#define WW 44
#define DD 59
#define BN (BB*NN)        // 24
#define PP (HH*WW)        // 704
#define CHO (CC+3)        // 83
#define WD (WW*DD)        // 2596
#define NQ4 (WD/4)        // 649
#define HLOC HH           // 16 rows per slab
#define DSTEP (0.9f/58.f)
#define GRIDB 498         // blocks
#define NPHASE 4          // 498*4 == 1992 == BN*CHO exactly

typedef float fx4 __attribute__((ext_vector_type(4)));

__device__ inline float waveMax(float v) {
#pragma unroll
    for (int o = 32; o; o >>= 1) v = fmaxf(v, __shfl_xor(v, o));
    return v;
}
__device__ inline float waveSum(float v) {
#pragma unroll
    for (int o = 32; o; o >>= 1) v += __shfl_xor(v, o);
    return v;
}

__global__ __launch_bounds__(256) void lss_all(const float* __restrict__ feats,
                                               const float* __restrict__ intr,
                                               const float* __restrict__ extr,
                                               float* __restrict__ out) {
    const int b   = blockIdx.x;
    const int tid = threadIdx.x;

    __shared__ float sf[PP];              // staged softmax channel (world only)
    __shared__ float valw[HLOC][WW + 1];  // per-row w-values (+1 pad for w+1 read)
    __shared__ float sred[4];
    __shared__ float sbc[2];

    // --- per-thread index tables: pure function of tid, reused across phases ---
    int   wA[3];
    int   cross[3][4];
    float sc[3][4];
#pragma unroll
    for (int i = 0; i < 3; ++i) {
        int q = tid + 256 * i;
        if (q < NQ4) {
            int base = 4 * q;
            int w    = base / DD;
            int dlo  = base - DD * w;
            wA[i] = w;
#pragma unroll
            for (int k = 0; k < 4; ++k) {
                int dd   = dlo + k;
                int cr   = (dd >= DD) ? 1 : 0;
                int deff = dd - cr * DD;
                cross[i][k] = cr;
                sc[i][k] = 0.1f + (float)deff * DSTEP;
            }
        }
    }
    if (tid < HLOC) valw[tid][WW] = 0.f;   // pad (read but never selected)

    for (int phase = 0; phase < NPHASE; ++phase) {
        const int s  = phase * GRIDB + b;     // slab = bn*CHO + ch
        const int ch = s % CHO;
        const int bn = s / CHO;
        const bool world = (ch < 3);

        __syncthreads();   // previous phase's readers done before LDS overwrite

        float tval = 0.f;
        if (world) {
            // --- softmax of channel C-1 over all 704 spatial positions ---
            const float* f = feats + ((size_t)bn * CC + (CC - 1)) * PP;
            float m = -1e30f;
            for (int p = tid; p < PP; p += 256) { float v = f[p]; sf[p] = v; m = fmaxf(m, v); }
            m = waveMax(m);
            if ((tid & 63) == 0) sred[tid >> 6] = m;
            __syncthreads();
            if (tid == 0) sbc[0] = fmaxf(fmaxf(sred[0], sred[1]), fmaxf(sred[2], sred[3]));
            __syncthreads();
            const float mm = sbc[0];
            float ssum = 0.f;
            for (int p = tid; p < PP; p += 256) { float e = expf(sf[p] - mm); sf[p] = e; ssum += e; }
            ssum = waveSum(ssum);
            if ((tid & 63) == 0) sred[tid >> 6] = ssum;
            __syncthreads();
            if (tid == 0) sbc[1] = sred[0] + sred[1] + sred[2] + sred[3];
            __syncthreads();
            const float inv = 1.0f / sbc[1];

            // --- row ch of M = R * K^-1 (uniform across threads) ---
            const float* K = intr + bn * 16;
            float a = K[0], bb2 = K[1], c = K[2];
            float d = K[4], e = K[5], ff = K[6];
            float g = K[8], h9 = K[9], i9 = K[10];
            float det = a * (e * i9 - ff * h9) - bb2 * (d * i9 - ff * g) + c * (d * h9 - e * g);
            float id = 1.0f / det;
            float kinv[9] = {
                (e * i9 - ff * h9) * id, (c * h9 - bb2 * i9) * id, (bb2 * ff - c * e) * id,
                (ff * g - d * i9) * id,  (a * i9 - c * g) * id,    (c * d - a * ff) * id,
                (d * h9 - e * g) * id,   (bb2 * g - a * h9) * id,  (a * e - bb2 * d) * id
            };
            const float* E = extr + bn * 16;
            float M0 = E[ch * 4 + 0] * kinv[0] + E[ch * 4 + 1] * kinv[3] + E[ch * 4 + 2] * kinv[6];
            float M1 = E[ch * 4 + 0] * kinv[1] + E[ch * 4 + 1] * kinv[4] + E[ch * 4 + 2] * kinv[7];
            float M2 = E[ch * 4 + 0] * kinv[2] + E[ch * 4 + 1] * kinv[5] + E[ch * 4 + 2] * kinv[8];
            tval = E[ch * 4 + 3];

            for (int t2 = tid; t2 < PP; t2 += 256) {
                int hl = t2 / WW;
                int w  = t2 - hl * WW;
                float ray = M0 * (float)w + M1 * (float)hl + M2;
                valw[hl][w] = ray * sf[t2] * inv;
            }
        } else {
            const float* frow = feats + ((size_t)bn * CC + (ch - 3)) * PP;
            for (int t2 = tid; t2 < PP; t2 += 256) {
                int hl = t2 / WW;
                int w  = t2 - hl * WW;
                valw[hl][w] = frow[t2];
            }
        }
        __syncthreads();

        float* obase = out + (size_t)s * HH * WD;

        if (world) {
            for (int hl = 0; hl < HLOC; ++hl) {
                const float* vr = valw[hl];
                float* orow = obase + (size_t)hl * WD;
#pragma unroll
                for (int i = 0; i < 3; ++i) {
                    int q = tid + 256 * i;
                    if (q < NQ4) {
                        float v0 = vr[wA[i]];
                        float v1 = vr[wA[i] + 1];
                        fx4 r;
                        r.x = (cross[i][0] ? v1 : v0) * sc[i][0] + tval;
                        r.y = (cross[i][1] ? v1 : v0) * sc[i][1] + tval;
                        r.z = (cross[i][2] ? v1 : v0) * sc[i][2] + tval;
                        r.w = (cross[i][3] ? v1 : v0) * sc[i][3] + tval;
                        *(fx4*)(orow + 4 * q) = r;
                    }
                }
            }
        } else {
            for (int hl = 0; hl < HLOC; ++hl) {
                const float* vr = valw[hl];
                float* orow = obase + (size_t)hl * WD;
#pragma unroll
                for (int i = 0; i < 3; ++i) {
                    int q = tid + 256 * i;
                    if (q < NQ4) {
                        float v0 = vr[wA[i]];
                        float v1 = vr[wA[i] + 1];
                        fx4 r;
                        r.x = cross[i][0] ? v1 : v0;
                        r.y = cross[i][1] ? v1 : v0;
                        r.z = cross[i][2] ? v1 : v0;
                        r.w = cross[i][3] ? v1 : v0;
                        *(fx4*)(orow + 4 * q) = r;
                    }
                }
            }
        }
    }
}

extern "C" void kernel_launch(void* const* d_in, const int* in_sizes, int n_in,
                              void* d_out, int out_size, void* d_ws, size_t ws_size,
                              hipStream_t stream) {
    const float* feats = (const float*)d_in[0];
    const float* intr  = (const float*)d_in[1];
    const float* extr  = (const float*)d_in[2];
    float* out = (float*)d_out;

    lss_all<<<GRIDB, 256, 0, stream>>>(feats, intr, extr, out);
}

// Round 7
// 67.688 us; speedup vs baseline: 1.0677x; 1.0677x over previous
//
#include <hip/hip_runtime.h>

// LiftSplatShoot: out(B,N,3+C,H,W,D) = concat(world, feats_broadcast)
// B=4 N=6 C=80 H=16 W=44 D=59 -> 82,739,712 fp32 (~331 MB). Write-bound.
// Round 7: fill-style FLAT grid-stride sweep. Row len 2596 and slab size
// 41536 are divisible by 4 => no float4 straddles a row/slab boundary, so
// each float4 needs only (vA, vB=next) from the source. Feature rows read
// feats directly (L1 broadcast, ~15 consecutive f's share one element);
// world rows (0.2% of work) read a tiny precomputed Vw table. All wave
// bursts are 1KB-aligned; machine sweeps output linearly like fillBuffer.

#define BB 4
#define NN 6
#define CC 80
#define HH 16
#define WW 44
#define DD 59
#define BN (BB*NN)        // 24
#define PP (HH*WW)        // 704
#define CHO (CC+3)        // 83
#define WD (WW*DD)        // 2596
#define DSTEP (0.9f/58.f)
#define NF4 20684928u     // 82,739,712 / 4
#define SWEEPB 2048

typedef float fx4 __attribute__((ext_vector_type(4)));
typedef unsigned int uint;

__device__ inline float waveMax(float v) {
#pragma unroll
    for (int o = 32; o; o >>= 1) v = fmaxf(v, __shfl_xor(v, o));
    return v;
}
__device__ inline float waveSum(float v) {
#pragma unroll
    for (int o = 32; o; o >>= 1) v += __shfl_xor(v, o);
    return v;
}

// One block per bn: softmax of channel 79, rows 0..2 of M = R*K^-1,
// Vw[(bn*3+ch)*704 + p] = ray*dlast, Tarr[bn*3+ch] = t.
__global__ __launch_bounds__(256) void lss_prep(const float* __restrict__ feats,
                                                const float* __restrict__ intr,
                                                const float* __restrict__ extr,
                                                float* __restrict__ Vw,
                                                float* __restrict__ Tarr) {
    const int bn = blockIdx.x;
    const int tid = threadIdx.x;
    __shared__ float sf[PP];
    __shared__ float sred[4];
    __shared__ float sbc[2];

    const float* f = feats + ((size_t)bn * CC + (CC - 1)) * PP;
    float m = -1e30f;
    for (int p = tid; p < PP; p += 256) { float v = f[p]; sf[p] = v; m = fmaxf(m, v); }
    m = waveMax(m);
    if ((tid & 63) == 0) sred[tid >> 6] = m;
    __syncthreads();
    if (tid == 0) sbc[0] = fmaxf(fmaxf(sred[0], sred[1]), fmaxf(sred[2], sred[3]));
    __syncthreads();
    const float mm = sbc[0];
    float s = 0.f;
    for (int p = tid; p < PP; p += 256) { float e = expf(sf[p] - mm); sf[p] = e; s += e; }
    s = waveSum(s);
    if ((tid & 63) == 0) sred[tid >> 6] = s;
    __syncthreads();
    if (tid == 0) sbc[1] = sred[0] + sred[1] + sred[2] + sred[3];
    __syncthreads();
    const float inv = 1.0f / sbc[1];

    // K^-1 (uniform across threads)
    const float* K = intr + bn * 16;
    float a = K[0], b = K[1], c = K[2];
    float d = K[4], e = K[5], ff = K[6];
    float g = K[8], h9 = K[9], i9 = K[10];
    float det = a * (e * i9 - ff * h9) - b * (d * i9 - ff * g) + c * (d * h9 - e * g);
    float id = 1.0f / det;
    float kinv[9] = {
        (e * i9 - ff * h9) * id, (c * h9 - b * i9) * id, (b * ff - c * e) * id,
        (ff * g - d * i9) * id,  (a * i9 - c * g) * id,  (c * d - a * ff) * id,
        (d * h9 - e * g) * id,   (b * g - a * h9) * id,  (a * e - b * d) * id
    };
    const float* E = extr + bn * 16;
#pragma unroll
    for (int ch = 0; ch < 3; ++ch) {
        float M0 = E[ch * 4 + 0] * kinv[0] + E[ch * 4 + 1] * kinv[3] + E[ch * 4 + 2] * kinv[6];
        float M1 = E[ch * 4 + 0] * kinv[1] + E[ch * 4 + 1] * kinv[4] + E[ch * 4 + 2] * kinv[7];
        float M2 = E[ch * 4 + 0] * kinv[2] + E[ch * 4 + 1] * kinv[5] + E[ch * 4 + 2] * kinv[8];
        float* vrow = Vw + (size_t)(bn * 3 + ch) * PP;
        for (int p = tid; p < PP; p += 256) {
            int hl = p / WW;
            int w  = p - hl * WW;
            float ray = M0 * (float)w + M1 * (float)hl + M2;
            vrow[p] = ray * sf[p] * inv;
        }
        if (tid == 0) Tarr[bn * 3 + ch] = E[ch * 4 + 3];
    }
}

// Flat grid-stride expansion: one float4 of output per thread-iteration.
__global__ __launch_bounds__(256) void lss_sweep(const float* __restrict__ feats,
                                                 const float* __restrict__ Vw,
                                                 const float* __restrict__ Tarr,
                                                 float* __restrict__ out) {
    const uint stride = gridDim.x * 256u;
    for (uint fq = blockIdx.x * 256u + threadIdx.x; fq < NF4; fq += stride) {
        uint r  = fq / 649u;           // global row (s*16 + hl)
        uint q  = fq - 649u * r;       // float4 index within row
        uint c  = q << 2;              // element col in row
        uint w  = c / 59u;
        uint d  = c - 59u * w;
        uint s  = r >> 4;              // slab = bn*83 + ch
        uint hl = r & 15u;
        uint bn = s / 83u;
        uint ch = s - 83u * bn;
        uint cw = (d >= 56u) ? 1u : 0u;   // does this float4 cross w -> w+1?
        uint kc = 59u - d;                 // first k that uses vB (>=4 if no cross)

        fx4 v;
        if (ch < 3u) {
            uint wrow = s - 80u * bn;      // bn*3 + ch
            uint widx = wrow * (uint)PP + hl * 44u + w;
            float T  = Tarr[wrow];
            float vA = Vw[widx];
            float vB = Vw[widx + cw];
#pragma unroll
            for (int k = 0; k < 4; ++k) {
                bool crossed = ((uint)k >= kc);
                float val = crossed ? vB : vA;
                uint dk = d + (uint)k - (crossed ? 59u : 0u);
                v[k] = val * (0.1f + (float)dk * DSTEP) + T;
            }
        } else {
            uint fi = (s - 3u * bn - 3u) * (uint)PP + hl * 44u + w;
            float vA = feats[fi];
            float vB = feats[fi + cw];
#pragma unroll
            for (int k = 0; k < 4; ++k) v[k] = ((uint)k >= kc) ? vB : vA;
        }
        ((fx4*)out)[fq] = v;
    }
}

extern "C" void kernel_launch(void* const* d_in, const int* in_sizes, int n_in,
                              void* d_out, int out_size, void* d_ws, size_t ws_size,
                              hipStream_t stream) {
    const float* feats = (const float*)d_in[0];
    const float* intr  = (const float*)d_in[1];
    const float* extr  = (const float*)d_in[2];
    float* out  = (float*)d_out;
    float* Vw   = (float*)d_ws;                 // 72*704 = 50688 floats
    float* Tarr = (float*)d_ws + 50688 + 16;    // 72 floats

    lss_prep<<<BN, 256, 0, stream>>>(feats, intr, extr, Vw, Tarr);
    lss_sweep<<<SWEEPB, 256, 0, stream>>>(feats, Vw, Tarr, out);
}